// Round 3
// baseline (2040.576 us; speedup 1.0000x reference)
//
#include <hip/hip_runtime.h>
#include <hip/hip_bf16.h>

using bf16 = __hip_bfloat16;

typedef float floatx4 __attribute__((ext_vector_type(4)));
typedef short shortx8 __attribute__((ext_vector_type(8)));
typedef __bf16 bf16x8 __attribute__((ext_vector_type(8)));

#define NEG_BIG -3.0e38f

__device__ __forceinline__ float bf2f(short s) {
  union { unsigned int u; float f; } x;
  x.u = ((unsigned int)(unsigned short)s) << 16;
  return x.f;
}

// ---------------- dtype sniff: cos[0]==1.0 exactly.
// fp32 -> word0 = 0x3F800000 ; bf16 -> word0 = 0x3F803F80 (two packed 1.0's)
__global__ void sniff_k(const void* __restrict__ cosp, int* __restrict__ flag) {
  unsigned w = *(const unsigned*)cosp;
  *flag = (w == 0x3F800000u) ? 1 : 0;  // 1 = inputs are fp32
}

// ---------------- generic input -> bf16 convert (flag-aware) ----------------
__global__ void conv_k(const void* __restrict__ src, bf16* __restrict__ dst, int n,
                       const int* __restrict__ flag) {
  int fp32 = *flag;
  int i = blockIdx.x * blockDim.x + threadIdx.x;
  if (i >= n) return;
  if (fp32) dst[i] = __float2bfloat16(((const float*)src)[i]);
  else      dst[i] = ((const bf16*)src)[i];
}

// ---------------- fused convert + transpose: src (2048, C) -> dst (C, 2048) bf16 ------
__global__ void transpose_conv_k(const void* __restrict__ src, bf16* __restrict__ dst,
                                 int C, const int* __restrict__ flag) {
  __shared__ bf16 tile[32][33];
  int fp32 = *flag;
  int tx = threadIdx.x, ty = threadIdx.y;
  int c0 = blockIdx.x * 32, r0 = blockIdx.y * 32;
#pragma unroll
  for (int i = 0; i < 32; i += 8) {
    size_t idx = (size_t)(r0 + ty + i) * C + c0 + tx;
    tile[ty + i][tx] = fp32 ? __float2bfloat16(((const float*)src)[idx])
                            : ((const bf16*)src)[idx];
  }
  __syncthreads();
#pragma unroll
  for (int i = 0; i < 32; i += 8)
    dst[(size_t)(c0 + ty + i) * 2048 + r0 + tx] = tile[tx][ty + i];
}

// ---------------- GEMM: C(M,N) = A(M,K) @ Bt(N,K)^T, bf16 in, fp32 acc ----------------
// Output dtype: bf16 normally; if (f32out_en && *flag) store fp32.
#define BM 128
#define BN 128
#define BK 32
#define LDK 40

__global__ __launch_bounds__(256) void gemm_bt(const bf16* __restrict__ A,
                                               const bf16* __restrict__ Bt,
                                               void* __restrict__ Cp,
                                               int M, int N, int K,
                                               const int* __restrict__ flag,
                                               int f32out_en) {
  __shared__ __align__(16) short sA[BM][LDK];
  __shared__ __align__(16) short sB[BN][LDK];
  const int f32out = f32out_en ? *flag : 0;
  const int tid = threadIdx.x;
  const int wave = tid >> 6, lane = tid & 63;
  const int wr = wave >> 1, wc = wave & 1;
  const int lrow = lane & 15, quad = lane >> 4;
  const int m0 = blockIdx.y * BM, n0 = blockIdx.x * BN;

  floatx4 acc[4][4];
#pragma unroll
  for (int r = 0; r < 4; ++r)
#pragma unroll
    for (int c = 0; c < 4; ++c)
      acc[r][c] = (floatx4){0.f, 0.f, 0.f, 0.f};

  const int srow = tid >> 1;
  const int shalf = (tid & 1) * 16;
  const bf16* gA = A + (size_t)(m0 + srow) * K + shalf;
  const bf16* gB = Bt + (size_t)(n0 + srow) * K + shalf;

  for (int kk = 0; kk < K; kk += BK) {
    int4 a0 = *(const int4*)(gA + kk);
    int4 a1 = *(const int4*)(gA + kk + 8);
    int4 b0 = *(const int4*)(gB + kk);
    int4 b1 = *(const int4*)(gB + kk + 8);
    *(int4*)&sA[srow][shalf]     = a0;
    *(int4*)&sA[srow][shalf + 8] = a1;
    *(int4*)&sB[srow][shalf]     = b0;
    *(int4*)&sB[srow][shalf + 8] = b1;
    __syncthreads();

    bf16x8 af[4], bfr[4];
#pragma unroll
    for (int r = 0; r < 4; ++r)
      af[r] = __builtin_bit_cast(bf16x8, *(const shortx8*)&sA[wr * 64 + r * 16 + lrow][quad * 8]);
#pragma unroll
    for (int c = 0; c < 4; ++c)
      bfr[c] = __builtin_bit_cast(bf16x8, *(const shortx8*)&sB[wc * 64 + c * 16 + lrow][quad * 8]);
#pragma unroll
    for (int r = 0; r < 4; ++r)
#pragma unroll
      for (int c = 0; c < 4; ++c)
        acc[r][c] = __builtin_amdgcn_mfma_f32_16x16x32_bf16(af[r], bfr[c], acc[r][c], 0, 0, 0);
    __syncthreads();
  }

#pragma unroll
  for (int r = 0; r < 4; ++r) {
#pragma unroll
    for (int c = 0; c < 4; ++c) {
      int mrow = m0 + wr * 64 + r * 16 + quad * 4;
      int ncol = n0 + wc * 64 + c * 16 + lrow;
      if (f32out) {
#pragma unroll
        for (int i = 0; i < 4; ++i)
          ((float*)Cp)[(size_t)(mrow + i) * N + ncol] = acc[r][c][i];
      } else {
#pragma unroll
        for (int i = 0; i < 4; ++i)
          ((bf16*)Cp)[(size_t)(mrow + i) * N + ncol] = __float2bfloat16(acc[r][c][i]);
      }
    }
  }
}

// ---------------- RoPE in-place on q (heads 0..31) and k (kv heads 0..7) ----------------
__global__ void rope_k(bf16* __restrict__ qkv, const bf16* __restrict__ cosb,
                       const bf16* __restrict__ sinb) {
  int idx = blockIdx.x * blockDim.x + threadIdx.x;
  int i = idx & 31;
  int head = (idx >> 5) % 40;
  int m = idx / (32 * 40);
  if (m >= 4096) return;
  int p = m & 2047;
  size_t base = (size_t)m * 3072 + (head < 32 ? head * 64 : 2048 + (head - 32) * 64);
  float c0 = __bfloat162float(cosb[p * 64 + i]);
  float s0 = __bfloat162float(sinb[p * 64 + i]);
  float c1 = __bfloat162float(cosb[p * 64 + 32 + i]);
  float s1 = __bfloat162float(sinb[p * 64 + 32 + i]);
  float a  = __bfloat162float(qkv[base + i]);
  float bb = __bfloat162float(qkv[base + 32 + i]);
  qkv[base + i]      = __float2bfloat16(a * c0 - bb * s0);
  qkv[base + 32 + i] = __float2bfloat16(bb * c1 + a * s1);
}

// ---------------- flash attention (causal, GQA 4:1), VALU version ----------------
// qkv: (4096, 3072) rows = b*2048+s; cols: q = h*64+hd, k = 2048+kvh*64+hd, v = 2560+kvh*64+hd
// No INF anywhere: masks use NEG_BIG; exp underflows to 0.
__global__ __launch_bounds__(256) void attn_k(const bf16* __restrict__ qkv,
                                              bf16* __restrict__ O) {
  const int S = 2048, LDQ = 3072, D = 2048;
  const int qt = blockIdx.x, h = blockIdx.y, b = blockIdx.z;
  const int kvh = h >> 2;
  const int tid = threadIdx.x;
  const int r = tid >> 2, c4 = tid & 3;
  const int q0 = qt * 64;
  const int qpos = q0 + r;

  __shared__ __align__(16) short sK[64][72];
  __shared__ __align__(16) short sV[64][72];
  __shared__ float sP[64][68];

  float qreg[64];
  {
    const bf16* qp = qkv + (size_t)(b * S + q0 + r) * LDQ + h * 64;
#pragma unroll
    for (int i = 0; i < 64; i += 8) {
      shortx8 v = *(const shortx8*)(qp + i);
#pragma unroll
      for (int e = 0; e < 8; ++e) qreg[i + e] = bf2f(v[e]);
    }
  }

  float m_i = NEG_BIG, l_i = 0.f;
  float oacc[16];
#pragma unroll
  for (int e = 0; e < 16; ++e) oacc[e] = 0.f;

  const int srow = tid >> 2, sseg = (tid & 3) * 16;

  for (int jt = 0; jt <= qt; ++jt) {
    const bf16* kp = qkv + (size_t)(b * S + jt * 64 + srow) * LDQ + 2048 + kvh * 64 + sseg;
    const bf16* vp = qkv + (size_t)(b * S + jt * 64 + srow) * LDQ + 2560 + kvh * 64 + sseg;
    *(int4*)&sK[srow][sseg]     = *(const int4*)kp;
    *(int4*)&sK[srow][sseg + 8] = *(const int4*)(kp + 8);
    *(int4*)&sV[srow][sseg]     = *(const int4*)vp;
    *(int4*)&sV[srow][sseg + 8] = *(const int4*)(vp + 8);
    __syncthreads();

    float sc[16];
#pragma unroll
    for (int cc = 0; cc < 16; ++cc) {
      int j = c4 * 16 + cc;
      float acc = 0.f;
#pragma unroll
      for (int i = 0; i < 64; i += 8) {
        shortx8 kv8 = *(const shortx8*)&sK[j][i];
#pragma unroll
        for (int e = 0; e < 8; ++e) acc = fmaf(qreg[i + e], bf2f(kv8[e]), acc);
      }
      int kpos = jt * 64 + j;
      sc[cc] = (kpos <= qpos) ? acc * 0.125f : NEG_BIG;
    }

    float tm = sc[0];
#pragma unroll
    for (int cc = 1; cc < 16; ++cc) tm = fmaxf(tm, sc[cc]);
    tm = fmaxf(tm, __shfl_xor(tm, 1));
    tm = fmaxf(tm, __shfl_xor(tm, 2));
    float Mn = fmaxf(m_i, tm);
    float alpha = __expf(m_i - Mn);
    float rs = 0.f;
#pragma unroll
    for (int cc = 0; cc < 16; ++cc) {
      float p = __expf(sc[cc] - Mn);
      sP[r][c4 * 16 + cc] = p;
      rs += p;
    }
    rs += __shfl_xor(rs, 1);
    rs += __shfl_xor(rs, 2);
    l_i = l_i * alpha + rs;
    m_i = Mn;
#pragma unroll
    for (int e = 0; e < 16; ++e) oacc[e] *= alpha;
    __syncthreads();

#pragma unroll 4
    for (int j = 0; j < 64; ++j) {
      float pj = sP[r][j];
      shortx8 v0 = *(const shortx8*)&sV[j][c4 * 16];
      shortx8 v1 = *(const shortx8*)&sV[j][c4 * 16 + 8];
#pragma unroll
      for (int e = 0; e < 8; ++e) oacc[e] = fmaf(pj, bf2f(v0[e]), oacc[e]);
#pragma unroll
      for (int e = 0; e < 8; ++e) oacc[8 + e] = fmaf(pj, bf2f(v1[e]), oacc[8 + e]);
    }
    __syncthreads();
  }

  float inv = 1.f / l_i;
  bf16* op = O + (size_t)(b * S + q0 + r) * D + h * 64 + c4 * 16;
#pragma unroll
  for (int e = 0; e < 16; ++e) op[e] = __float2bfloat16(oacc[e] * inv);
}

// ---------------- launch ----------------
// ws layout (bf16 elements from ws16 = d_ws + 16; flag int at d_ws):
//   xb     8,388,608   (4096 x 2048)  | aliased later by o (same size)
//   cosb     131,072
//   sinb     131,072
//   bt_qkv 6,291,456   (3072 x 2048)
//   wot    4,194,304   (2048 x 2048)
//   qkv   12,582,912   (4096 x 3072)
// total ~63.4 MB
extern "C" void kernel_launch(void* const* d_in, const int* in_sizes, int n_in,
                              void* d_out, int out_size, void* d_ws, size_t ws_size,
                              hipStream_t stream) {
  const void* x    = d_in[0];
  const void* cosp = d_in[1];
  const void* sinp = d_in[2];
  const void* wq   = d_in[3];
  const void* wk   = d_in[4];
  const void* wv   = d_in[5];
  const void* wo   = d_in[6];

  int* flag = (int*)d_ws;
  bf16* ws16 = (bf16*)((char*)d_ws + 16);
  bf16* xb     = ws16;
  bf16* cosb   = xb + (size_t)8388608;
  bf16* sinb   = cosb + 131072;
  bf16* bt_qkv = sinb + 131072;
  bf16* wot    = bt_qkv + (size_t)3072 * 2048;
  bf16* qkv    = wot + (size_t)2048 * 2048;
  bf16* o      = xb;  // x dead after QKV GEMM; attn output reuses it

  sniff_k<<<1, 1, 0, stream>>>(cosp, flag);

  conv_k<<<(8388608 + 255) / 256, 256, 0, stream>>>(x, xb, 8388608, flag);
  conv_k<<<(131072 + 255) / 256, 256, 0, stream>>>(cosp, cosb, 131072, flag);
  conv_k<<<(131072 + 255) / 256, 256, 0, stream>>>(sinp, sinb, 131072, flag);

  dim3 tb(32, 8);
  transpose_conv_k<<<dim3(64, 64), tb, 0, stream>>>(wq, bt_qkv, 2048, flag);
  transpose_conv_k<<<dim3(16, 64), tb, 0, stream>>>(wk, bt_qkv + (size_t)2048 * 2048, 512, flag);
  transpose_conv_k<<<dim3(16, 64), tb, 0, stream>>>(wv, bt_qkv + (size_t)2560 * 2048, 512, flag);
  transpose_conv_k<<<dim3(64, 64), tb, 0, stream>>>(wo, wot, 2048, flag);

  // QKV projection: (4096,2048) @ (2048,3072), bf16 out
  gemm_bt<<<dim3(3072 / BN, 4096 / BM), 256, 0, stream>>>(xb, bt_qkv, qkv,
                                                          4096, 3072, 2048, flag, 0);

  rope_k<<<20480, 256, 0, stream>>>(qkv, cosb, sinb);

  attn_k<<<dim3(32, 32, 2), 256, 0, stream>>>(qkv, o);

  // output projection: (4096,2048) @ (2048,2048); output dtype follows input dtype
  gemm_bt<<<dim3(2048 / BN, 4096 / BM), 256, 0, stream>>>(o, wot, d_out,
                                                          4096, 2048, 2048, flag, 1);
}

// Round 4
// 581.294 us; speedup vs baseline: 3.5104x; 3.5104x over previous
//
#include <hip/hip_runtime.h>
#include <hip/hip_bf16.h>

using bf16 = __hip_bfloat16;

typedef float floatx4 __attribute__((ext_vector_type(4)));
typedef short shortx8 __attribute__((ext_vector_type(8)));
typedef __bf16 bf16x8 __attribute__((ext_vector_type(8)));

#define NEG_BIG -3.0e38f

__device__ __forceinline__ float bf2f(short s) {
  union { unsigned int u; float f; } x;
  x.u = ((unsigned int)(unsigned short)s) << 16;
  return x.f;
}

// ---------------- dtype sniff: cos[0]==1.0 exactly.
// fp32 -> word0 = 0x3F800000 ; bf16 -> word0 = 0x3F803F80 (two packed 1.0's)
__global__ void sniff_k(const void* __restrict__ cosp, int* __restrict__ flag) {
  unsigned w = *(const unsigned*)cosp;
  *flag = (w == 0x3F800000u) ? 1 : 0;  // 1 = inputs are fp32
}

// ---------------- generic input -> bf16 convert (flag-aware) ----------------
__global__ void conv_k(const void* __restrict__ src, bf16* __restrict__ dst, int n,
                       const int* __restrict__ flag) {
  int fp32 = *flag;
  int i = blockIdx.x * blockDim.x + threadIdx.x;
  if (i >= n) return;
  if (fp32) dst[i] = __float2bfloat16(((const float*)src)[i]);
  else      dst[i] = ((const bf16*)src)[i];
}

// ---------------- fused convert + transpose: src (2048, C) -> dst (C, 2048) bf16 ------
__global__ void transpose_conv_k(const void* __restrict__ src, bf16* __restrict__ dst,
                                 int C, const int* __restrict__ flag) {
  __shared__ bf16 tile[32][33];
  int fp32 = *flag;
  int tx = threadIdx.x, ty = threadIdx.y;
  int c0 = blockIdx.x * 32, r0 = blockIdx.y * 32;
#pragma unroll
  for (int i = 0; i < 32; i += 8) {
    size_t idx = (size_t)(r0 + ty + i) * C + c0 + tx;
    tile[ty + i][tx] = fp32 ? __float2bfloat16(((const float*)src)[idx])
                            : ((const bf16*)src)[idx];
  }
  __syncthreads();
#pragma unroll
  for (int i = 0; i < 32; i += 8)
    dst[(size_t)(c0 + ty + i) * 2048 + r0 + tx] = tile[tx][ty + i];
}

// ---------------- GEMM: C(M,N) = A(M,K) @ Bt(N,K)^T, bf16 in, fp32 acc ----------------
#define BM 128
#define BN 128
#define BK 32
#define LDK 40

__global__ __launch_bounds__(256) void gemm_bt(const bf16* __restrict__ A,
                                               const bf16* __restrict__ Bt,
                                               void* __restrict__ Cp,
                                               int M, int N, int K,
                                               const int* __restrict__ flag,
                                               int f32out_en) {
  __shared__ __align__(16) short sA[BM][LDK];
  __shared__ __align__(16) short sB[BN][LDK];
  const int f32out = f32out_en ? *flag : 0;
  const int tid = threadIdx.x;
  const int wave = tid >> 6, lane = tid & 63;
  const int wr = wave >> 1, wc = wave & 1;
  const int lrow = lane & 15, quad = lane >> 4;
  const int m0 = blockIdx.y * BM, n0 = blockIdx.x * BN;

  floatx4 acc[4][4];
#pragma unroll
  for (int r = 0; r < 4; ++r)
#pragma unroll
    for (int c = 0; c < 4; ++c)
      acc[r][c] = (floatx4){0.f, 0.f, 0.f, 0.f};

  const int srow = tid >> 1;
  const int shalf = (tid & 1) * 16;
  const bf16* gA = A + (size_t)(m0 + srow) * K + shalf;
  const bf16* gB = Bt + (size_t)(n0 + srow) * K + shalf;

  for (int kk = 0; kk < K; kk += BK) {
    int4 a0 = *(const int4*)(gA + kk);
    int4 a1 = *(const int4*)(gA + kk + 8);
    int4 b0 = *(const int4*)(gB + kk);
    int4 b1 = *(const int4*)(gB + kk + 8);
    *(int4*)&sA[srow][shalf]     = a0;
    *(int4*)&sA[srow][shalf + 8] = a1;
    *(int4*)&sB[srow][shalf]     = b0;
    *(int4*)&sB[srow][shalf + 8] = b1;
    __syncthreads();

    bf16x8 af[4], bfr[4];
#pragma unroll
    for (int r = 0; r < 4; ++r)
      af[r] = __builtin_bit_cast(bf16x8, *(const shortx8*)&sA[wr * 64 + r * 16 + lrow][quad * 8]);
#pragma unroll
    for (int c = 0; c < 4; ++c)
      bfr[c] = __builtin_bit_cast(bf16x8, *(const shortx8*)&sB[wc * 64 + c * 16 + lrow][quad * 8]);
#pragma unroll
    for (int r = 0; r < 4; ++r)
#pragma unroll
      for (int c = 0; c < 4; ++c)
        acc[r][c] = __builtin_amdgcn_mfma_f32_16x16x32_bf16(af[r], bfr[c], acc[r][c], 0, 0, 0);
    __syncthreads();
  }

#pragma unroll
  for (int r = 0; r < 4; ++r) {
#pragma unroll
    for (int c = 0; c < 4; ++c) {
      int mrow = m0 + wr * 64 + r * 16 + quad * 4;
      int ncol = n0 + wc * 64 + c * 16 + lrow;
      if (f32out) {
#pragma unroll
        for (int i = 0; i < 4; ++i)
          ((float*)Cp)[(size_t)(mrow + i) * N + ncol] = acc[r][c][i];
      } else {
#pragma unroll
        for (int i = 0; i < 4; ++i)
          ((bf16*)Cp)[(size_t)(mrow + i) * N + ncol] = __float2bfloat16(acc[r][c][i]);
      }
    }
  }
}

// ---------------- RoPE in-place on q (heads 0..31) and k (kv heads 0..7) ----------------
__global__ void rope_k(bf16* __restrict__ qkv, const bf16* __restrict__ cosb,
                       const bf16* __restrict__ sinb) {
  int idx = blockIdx.x * blockDim.x + threadIdx.x;
  int i = idx & 31;
  int head = (idx >> 5) % 40;
  int m = idx / (32 * 40);
  if (m >= 4096) return;
  int p = m & 2047;
  size_t base = (size_t)m * 3072 + (head < 32 ? head * 64 : 2048 + (head - 32) * 64);
  float c0 = __bfloat162float(cosb[p * 64 + i]);
  float s0 = __bfloat162float(sinb[p * 64 + i]);
  float c1 = __bfloat162float(cosb[p * 64 + 32 + i]);
  float s1 = __bfloat162float(sinb[p * 64 + 32 + i]);
  float a  = __bfloat162float(qkv[base + i]);
  float bb = __bfloat162float(qkv[base + 32 + i]);
  qkv[base + i]      = __float2bfloat16(a * c0 - bb * s0);
  qkv[base + 32 + i] = __float2bfloat16(bb * c1 + a * s1);
}

// ---------------- flash attention (causal, GQA 4:1) — MFMA version ----------------
// qkv: (4096, 3072) rows = b*2048+s; cols: q = h*64+hd, k = 2048+kvh*64+hd, v = 2560+kvh*64+hd
// Block: 256 thr = 4 waves; Q-tile 64 rows (16/wave); K/V tiles 64.
// MFMA 16x16x32: A-frag A[m=lane&15][k=quad*8+j]; B-frag B[k=quad*8+j][n=lane&15];
// C/D: D[row=quad*4+i][col=lane&15]  (m89/m91-verified layouts).
__global__ __launch_bounds__(256) void attn_k(const bf16* __restrict__ qkv,
                                              bf16* __restrict__ O) {
  const int S = 2048, LDQ = 3072, D = 2048;
  const int qt = blockIdx.x, h = blockIdx.y, b = blockIdx.z;
  const int kvh = h >> 2;
  const int tid = threadIdx.x;
  const int w = tid >> 6, lane = tid & 63;
  const int quad = lane >> 4, l15 = lane & 15;
  const int q0 = qt * 64;

  __shared__ __align__(16) short sK [64][72];   // [kv pos][hd]
  __shared__ __align__(16) short sVt[64][72];   // [hd][kv pos]  (transposed)
  __shared__ __align__(16) short sP [4][16][72]; // per-wave P round-trip

  // Q fragments (held in registers for the whole block)
  bf16x8 qa[2];
  {
    const bf16* qp = qkv + (size_t)(b * S + q0 + w * 16 + l15) * LDQ + h * 64 + quad * 8;
    qa[0] = __builtin_bit_cast(bf16x8, *(const shortx8*)qp);
    qa[1] = __builtin_bit_cast(bf16x8, *(const shortx8*)(qp + 32));
  }

  floatx4 oacc[4];
#pragma unroll
  for (int d = 0; d < 4; ++d) oacc[d] = (floatx4){0.f, 0.f, 0.f, 0.f};
  float m_i[4], l_i[4];
#pragma unroll
  for (int i = 0; i < 4; ++i) { m_i[i] = NEG_BIG; l_i[i] = 0.f; }

  const int srow = tid >> 2, sseg = (tid & 3) * 16;
  const bf16* kvbase = qkv + (size_t)(b * S) * LDQ + 2048 + kvh * 64 + sseg;

  for (int jt = 0; jt <= qt; ++jt) {
    // ---- stage K (row layout) and V (transposed) ----
    const bf16* kp = kvbase + (size_t)(jt * 64 + srow) * LDQ;
    int4 k0 = *(const int4*)kp;
    int4 k1 = *(const int4*)(kp + 8);
    int4 v0 = *(const int4*)(kp + 512);      // V is 512 cols after K
    int4 v1 = *(const int4*)(kp + 520);
    *(int4*)&sK[srow][sseg]     = k0;
    *(int4*)&sK[srow][sseg + 8] = k1;
    const short* v0s = (const short*)&v0;
    const short* v1s = (const short*)&v1;
#pragma unroll
    for (int e = 0; e < 8; ++e) sVt[sseg + e][srow]     = v0s[e];
#pragma unroll
    for (int e = 0; e < 8; ++e) sVt[sseg + 8 + e][srow] = v1s[e];
    __syncthreads();

    // ---- S = Q K^T (16x64 per wave) ----
    floatx4 sfr[4];
#pragma unroll
    for (int nb = 0; nb < 4; ++nb) sfr[nb] = (floatx4){0.f, 0.f, 0.f, 0.f};
#pragma unroll
    for (int kk = 0; kk < 2; ++kk) {
#pragma unroll
      for (int nb = 0; nb < 4; ++nb) {
        bf16x8 bfr = __builtin_bit_cast(bf16x8,
            *(const shortx8*)&sK[nb * 16 + l15][kk * 32 + quad * 8]);
        sfr[nb] = __builtin_amdgcn_mfma_f32_16x16x32_bf16(qa[kk], bfr, sfr[nb], 0, 0, 0);
      }
    }

    // ---- scale + (diagonal-only) causal mask ----
    float sc[4][4];
#pragma unroll
    for (int nb = 0; nb < 4; ++nb)
#pragma unroll
      for (int i = 0; i < 4; ++i) sc[nb][i] = sfr[nb][i] * 0.125f;
    if (jt == qt) {
#pragma unroll
      for (int nb = 0; nb < 4; ++nb) {
        int kloc = nb * 16 + l15;
#pragma unroll
        for (int i = 0; i < 4; ++i)
          if (kloc > w * 16 + quad * 4 + i) sc[nb][i] = NEG_BIG;
      }
    }

    // ---- online softmax (rows = quad*4+i, reduce over 16 lanes of the quad) ----
    float rmax[4], rs[4], alpha[4];
#pragma unroll
    for (int i = 0; i < 4; ++i) {
      float m = fmaxf(fmaxf(sc[0][i], sc[1][i]), fmaxf(sc[2][i], sc[3][i]));
      m = fmaxf(m, __shfl_xor(m, 1));
      m = fmaxf(m, __shfl_xor(m, 2));
      m = fmaxf(m, __shfl_xor(m, 4));
      m = fmaxf(m, __shfl_xor(m, 8));
      rmax[i] = m;
    }
#pragma unroll
    for (int i = 0; i < 4; ++i) {
      float Mn = fmaxf(m_i[i], rmax[i]);
      alpha[i] = __expf(m_i[i] - Mn);
      m_i[i] = Mn;
      rs[i] = 0.f;
    }
#pragma unroll
    for (int nb = 0; nb < 4; ++nb)
#pragma unroll
      for (int i = 0; i < 4; ++i) {
        float p = __expf(sc[nb][i] - m_i[i]);
        rs[i] += p;
        sP[w][quad * 4 + i][nb * 16 + l15] = (short)__bfloat16_as_ushort(__float2bfloat16(p));
      }
#pragma unroll
    for (int i = 0; i < 4; ++i) {
      float r = rs[i];
      r += __shfl_xor(r, 1);
      r += __shfl_xor(r, 2);
      r += __shfl_xor(r, 4);
      r += __shfl_xor(r, 8);
      l_i[i] = l_i[i] * alpha[i] + r;
    }
#pragma unroll
    for (int d = 0; d < 4; ++d)
#pragma unroll
      for (int i = 0; i < 4; ++i) oacc[d][i] *= alpha[i];

    // ---- O += P V (P from per-wave LDS round-trip; V^T B-frags) ----
#pragma unroll
    for (int kk = 0; kk < 2; ++kk) {
      bf16x8 afr = __builtin_bit_cast(bf16x8,
          *(const shortx8*)&sP[w][l15][kk * 32 + quad * 8]);
#pragma unroll
      for (int d = 0; d < 4; ++d) {
        bf16x8 bfr = __builtin_bit_cast(bf16x8,
            *(const shortx8*)&sVt[d * 16 + l15][kk * 32 + quad * 8]);
        oacc[d] = __builtin_amdgcn_mfma_f32_16x16x32_bf16(afr, bfr, oacc[d], 0, 0, 0);
      }
    }
    __syncthreads();  // before next tile overwrites sK/sVt
  }

  // ---- epilogue: O /= l, store ----
#pragma unroll
  for (int i = 0; i < 4; ++i) {
    float inv = 1.f / l_i[i];
    bf16* op = O + (size_t)(b * S + q0 + w * 16 + quad * 4 + i) * D + h * 64 + l15;
#pragma unroll
    for (int d = 0; d < 4; ++d)
      op[d * 16] = __float2bfloat16(oacc[d][i] * inv);
  }
}

// ---------------- launch ----------------
// ws layout (bf16 elements from ws16 = d_ws + 16; flag int at d_ws):
//   xb 8.4M | cosb/sinb 131k | bt_qkv 6.3M | wot 4.2M | qkv 12.6M  (~63.4 MB)
extern "C" void kernel_launch(void* const* d_in, const int* in_sizes, int n_in,
                              void* d_out, int out_size, void* d_ws, size_t ws_size,
                              hipStream_t stream) {
  const void* x    = d_in[0];
  const void* cosp = d_in[1];
  const void* sinp = d_in[2];
  const void* wq   = d_in[3];
  const void* wk   = d_in[4];
  const void* wv   = d_in[5];
  const void* wo   = d_in[6];

  int* flag = (int*)d_ws;
  bf16* ws16 = (bf16*)((char*)d_ws + 16);
  bf16* xb     = ws16;
  bf16* cosb   = xb + (size_t)8388608;
  bf16* sinb   = cosb + 131072;
  bf16* bt_qkv = sinb + 131072;
  bf16* wot    = bt_qkv + (size_t)3072 * 2048;
  bf16* qkv    = wot + (size_t)2048 * 2048;
  bf16* o      = xb;  // x dead after QKV GEMM; attn output reuses it

  sniff_k<<<1, 1, 0, stream>>>(cosp, flag);

  conv_k<<<(8388608 + 255) / 256, 256, 0, stream>>>(x, xb, 8388608, flag);
  conv_k<<<(131072 + 255) / 256, 256, 0, stream>>>(cosp, cosb, 131072, flag);
  conv_k<<<(131072 + 255) / 256, 256, 0, stream>>>(sinp, sinb, 131072, flag);

  dim3 tb(32, 8);
  transpose_conv_k<<<dim3(64, 64), tb, 0, stream>>>(wq, bt_qkv, 2048, flag);
  transpose_conv_k<<<dim3(16, 64), tb, 0, stream>>>(wk, bt_qkv + (size_t)2048 * 2048, 512, flag);
  transpose_conv_k<<<dim3(16, 64), tb, 0, stream>>>(wv, bt_qkv + (size_t)2560 * 2048, 512, flag);
  transpose_conv_k<<<dim3(64, 64), tb, 0, stream>>>(wo, wot, 2048, flag);

  // QKV projection: (4096,2048) @ (2048,3072), bf16 out
  gemm_bt<<<dim3(3072 / BN, 4096 / BM), 256, 0, stream>>>(xb, bt_qkv, qkv,
                                                          4096, 3072, 2048, flag, 0);

  rope_k<<<20480, 256, 0, stream>>>(qkv, cosb, sinb);

  attn_k<<<dim3(32, 32, 2), 256, 0, stream>>>(qkv, o);

  // output projection: (4096,2048) @ (2048,2048); output dtype follows input dtype
  gemm_bt<<<dim3(2048 / BN, 4096 / BM), 256, 0, stream>>>(o, wot, d_out,
                                                          4096, 2048, 2048, flag, 1);
}

// Round 5
// 457.308 us; speedup vs baseline: 4.4621x; 1.2711x over previous
//
#include <hip/hip_runtime.h>
#include <hip/hip_bf16.h>

using bf16 = __hip_bfloat16;

typedef float floatx4 __attribute__((ext_vector_type(4)));
typedef short shortx8 __attribute__((ext_vector_type(8)));
typedef __bf16 bf16x8 __attribute__((ext_vector_type(8)));

#define NEG_BIG -3.0e38f

__device__ __forceinline__ float bf2f(short s) {
  union { unsigned int u; float f; } x;
  x.u = ((unsigned int)(unsigned short)s) << 16;
  return x.f;
}

// ---------------- dtype sniff: cos[0]==1.0 exactly.
// fp32 -> word0 = 0x3F800000 ; bf16 -> word0 = 0x3F803F80 (two packed 1.0's)
__global__ void sniff_k(const void* __restrict__ cosp, int* __restrict__ flag) {
  unsigned w = *(const unsigned*)cosp;
  *flag = (w == 0x3F800000u) ? 1 : 0;  // 1 = inputs are fp32
}

// ---------------- generic input -> bf16 convert (flag-aware) ----------------
__global__ void conv_k(const void* __restrict__ src, bf16* __restrict__ dst, int n,
                       const int* __restrict__ flag) {
  int fp32 = *flag;
  int i = blockIdx.x * blockDim.x + threadIdx.x;
  if (i >= n) return;
  if (fp32) dst[i] = __float2bfloat16(((const float*)src)[i]);
  else      dst[i] = ((const bf16*)src)[i];
}

// ---------------- fused convert + transpose: src (2048, C) -> dst (C, 2048) bf16 ------
__global__ void transpose_conv_k(const void* __restrict__ src, bf16* __restrict__ dst,
                                 int C, const int* __restrict__ flag) {
  __shared__ bf16 tile[32][33];
  int fp32 = *flag;
  int tx = threadIdx.x, ty = threadIdx.y;
  int c0 = blockIdx.x * 32, r0 = blockIdx.y * 32;
#pragma unroll
  for (int i = 0; i < 32; i += 8) {
    size_t idx = (size_t)(r0 + ty + i) * C + c0 + tx;
    tile[ty + i][tx] = fp32 ? __float2bfloat16(((const float*)src)[idx])
                            : ((const bf16*)src)[idx];
  }
  __syncthreads();
#pragma unroll
  for (int i = 0; i < 32; i += 8)
    dst[(size_t)(c0 + ty + i) * 2048 + r0 + tx] = tile[tx][ty + i];
}

// ---------------- GEMM: C(M,N) = A(M,K) @ Bt(N,K)^T, bf16 in, fp32 acc ----------------
#define BM 128
#define BN 128
#define BK 32
#define LDK 40

__global__ __launch_bounds__(256) void gemm_bt(const bf16* __restrict__ A,
                                               const bf16* __restrict__ Bt,
                                               void* __restrict__ Cp,
                                               int M, int N, int K,
                                               const int* __restrict__ flag,
                                               int f32out_en) {
  __shared__ __align__(16) short sA[BM][LDK];
  __shared__ __align__(16) short sB[BN][LDK];
  const int f32out = f32out_en ? *flag : 0;
  const int tid = threadIdx.x;
  const int wave = tid >> 6, lane = tid & 63;
  const int wr = wave >> 1, wc = wave & 1;
  const int lrow = lane & 15, quad = lane >> 4;
  const int m0 = blockIdx.y * BM, n0 = blockIdx.x * BN;

  floatx4 acc[4][4];
#pragma unroll
  for (int r = 0; r < 4; ++r)
#pragma unroll
    for (int c = 0; c < 4; ++c)
      acc[r][c] = (floatx4){0.f, 0.f, 0.f, 0.f};

  const int srow = tid >> 1;
  const int shalf = (tid & 1) * 16;
  const bf16* gA = A + (size_t)(m0 + srow) * K + shalf;
  const bf16* gB = Bt + (size_t)(n0 + srow) * K + shalf;

  for (int kk = 0; kk < K; kk += BK) {
    int4 a0 = *(const int4*)(gA + kk);
    int4 a1 = *(const int4*)(gA + kk + 8);
    int4 b0 = *(const int4*)(gB + kk);
    int4 b1 = *(const int4*)(gB + kk + 8);
    *(int4*)&sA[srow][shalf]     = a0;
    *(int4*)&sA[srow][shalf + 8] = a1;
    *(int4*)&sB[srow][shalf]     = b0;
    *(int4*)&sB[srow][shalf + 8] = b1;
    __syncthreads();

    bf16x8 af[4], bfr[4];
#pragma unroll
    for (int r = 0; r < 4; ++r)
      af[r] = __builtin_bit_cast(bf16x8, *(const shortx8*)&sA[wr * 64 + r * 16 + lrow][quad * 8]);
#pragma unroll
    for (int c = 0; c < 4; ++c)
      bfr[c] = __builtin_bit_cast(bf16x8, *(const shortx8*)&sB[wc * 64 + c * 16 + lrow][quad * 8]);
#pragma unroll
    for (int r = 0; r < 4; ++r)
#pragma unroll
      for (int c = 0; c < 4; ++c)
        acc[r][c] = __builtin_amdgcn_mfma_f32_16x16x32_bf16(af[r], bfr[c], acc[r][c], 0, 0, 0);
    __syncthreads();
  }

#pragma unroll
  for (int r = 0; r < 4; ++r) {
#pragma unroll
    for (int c = 0; c < 4; ++c) {
      int mrow = m0 + wr * 64 + r * 16 + quad * 4;
      int ncol = n0 + wc * 64 + c * 16 + lrow;
      if (f32out) {
#pragma unroll
        for (int i = 0; i < 4; ++i)
          ((float*)Cp)[(size_t)(mrow + i) * N + ncol] = acc[r][c][i];
      } else {
#pragma unroll
        for (int i = 0; i < 4; ++i)
          ((bf16*)Cp)[(size_t)(mrow + i) * N + ncol] = __float2bfloat16(acc[r][c][i]);
      }
    }
  }
}

// ---------------- RoPE in-place on q (heads 0..31) and k (kv heads 0..7) ----------------
__global__ void rope_k(bf16* __restrict__ qkv, const bf16* __restrict__ cosb,
                       const bf16* __restrict__ sinb) {
  int idx = blockIdx.x * blockDim.x + threadIdx.x;
  int i = idx & 31;
  int head = (idx >> 5) % 40;
  int m = idx / (32 * 40);
  if (m >= 4096) return;
  int p = m & 2047;
  size_t base = (size_t)m * 3072 + (head < 32 ? head * 64 : 2048 + (head - 32) * 64);
  float c0 = __bfloat162float(cosb[p * 64 + i]);
  float s0 = __bfloat162float(sinb[p * 64 + i]);
  float c1 = __bfloat162float(cosb[p * 64 + 32 + i]);
  float s1 = __bfloat162float(sinb[p * 64 + 32 + i]);
  float a  = __bfloat162float(qkv[base + i]);
  float bb = __bfloat162float(qkv[base + 32 + i]);
  qkv[base + i]      = __float2bfloat16(a * c0 - bb * s0);
  qkv[base + 32 + i] = __float2bfloat16(bb * c1 + a * s1);
}

// ---------------- flash attention (causal, GQA 4:1) — MFMA, balanced + prefetch ------
// qkv: (4096, 3072) rows = b*2048+s; cols: q = h*64+hd, k = 2048+kvh*64+hd, v = 2560+kvh*64+hd
// Block = 4 waves; processes q-tile PAIR (p, 31-p): constant 33 k-tile iterations.
// sVt bank-swizzle: logical col j of row d stored at (j + (d&56)) & 63 — staging
// writes hit 64 distinct columns (<=2-way, free), reads stay 8-contiguous/16B-aligned.
// K/V for tile jt+1 prefetched into registers during tile jt's compute.
__global__ __launch_bounds__(256) void attn_k(const bf16* __restrict__ qkv,
                                              bf16* __restrict__ O) {
  const int S = 2048, LDQ = 3072, D = 2048;
  const int p = blockIdx.x, h = blockIdx.y, b = blockIdx.z;
  const int kvh = h >> 2;
  const int tid = threadIdx.x;
  const int w = tid >> 6, lane = tid & 63;
  const int quad = lane >> 4, l15 = lane & 15;

  __shared__ __align__(16) short sK [64][72];   // [kv pos][hd]
  __shared__ __align__(16) short sVt[64][72];   // [hd][swizzled kv pos]
  __shared__ __align__(16) short sP [4][16][72]; // per-wave P round-trip

  const int srow = tid >> 2, sseg = (tid & 3) * 16;
  const bf16* kvbase = qkv + (size_t)(b * S) * LDQ + 2048 + kvh * 64 + sseg;

  for (int phase = 0; phase < 2; ++phase) {
    const int qt = phase ? (31 - p) : p;
    const int q0 = qt * 64;

    // Q fragments for this phase
    bf16x8 qa[2];
    {
      const bf16* qp = qkv + (size_t)(b * S + q0 + w * 16 + l15) * LDQ + h * 64 + quad * 8;
      qa[0] = __builtin_bit_cast(bf16x8, *(const shortx8*)qp);
      qa[1] = __builtin_bit_cast(bf16x8, *(const shortx8*)(qp + 32));
    }

    floatx4 oacc[4];
#pragma unroll
    for (int d = 0; d < 4; ++d) oacc[d] = (floatx4){0.f, 0.f, 0.f, 0.f};
    float m_i[4], l_p[4];  // l_p: lane-partial row sum (reduced once in epilogue)
#pragma unroll
    for (int i = 0; i < 4; ++i) { m_i[i] = NEG_BIG; l_p[i] = 0.f; }

    const int jtEnd = qt + 1;
    // prefetch tile 0
    const bf16* kp = kvbase + (size_t)srow * LDQ;
    int4 kr0 = *(const int4*)kp;
    int4 kr1 = *(const int4*)(kp + 8);
    int4 vr0 = *(const int4*)(kp + 512);
    int4 vr1 = *(const int4*)(kp + 520);

    for (int jt = 0; jt < jtEnd; ++jt) {
      // ---- stage prefetched K (row layout) and V (transposed, bank-swizzled) ----
      *(int4*)&sK[srow][sseg]     = kr0;
      *(int4*)&sK[srow][sseg + 8] = kr1;
      {
        const short* v0s = (const short*)&vr0;
        const short* v1s = (const short*)&vr1;
#pragma unroll
        for (int e = 0; e < 8; ++e) {
          int d = sseg + e;
          sVt[d][(srow + (d & 56)) & 63] = v0s[e];
        }
#pragma unroll
        for (int e = 0; e < 8; ++e) {
          int d = sseg + 8 + e;
          sVt[d][(srow + (d & 56)) & 63] = v1s[e];
        }
      }
      // ---- prefetch next tile while LDS settles / compute runs ----
      if (jt + 1 < jtEnd) {
        const bf16* kp2 = kvbase + (size_t)((jt + 1) * 64 + srow) * LDQ;
        kr0 = *(const int4*)kp2;
        kr1 = *(const int4*)(kp2 + 8);
        vr0 = *(const int4*)(kp2 + 512);
        vr1 = *(const int4*)(kp2 + 520);
      }
      __syncthreads();

      // ---- S = Q K^T (16x64 per wave) ----
      floatx4 sfr[4];
#pragma unroll
      for (int nb = 0; nb < 4; ++nb) sfr[nb] = (floatx4){0.f, 0.f, 0.f, 0.f};
#pragma unroll
      for (int kk = 0; kk < 2; ++kk) {
#pragma unroll
        for (int nb = 0; nb < 4; ++nb) {
          bf16x8 bfr = __builtin_bit_cast(bf16x8,
              *(const shortx8*)&sK[nb * 16 + l15][kk * 32 + quad * 8]);
          sfr[nb] = __builtin_amdgcn_mfma_f32_16x16x32_bf16(qa[kk], bfr, sfr[nb], 0, 0, 0);
        }
      }

      // ---- scale + (diagonal-only) causal mask ----
      float sc[4][4];
#pragma unroll
      for (int nb = 0; nb < 4; ++nb)
#pragma unroll
        for (int i = 0; i < 4; ++i) sc[nb][i] = sfr[nb][i] * 0.125f;
      if (jt == qt) {
#pragma unroll
        for (int nb = 0; nb < 4; ++nb) {
          int kloc = nb * 16 + l15;
#pragma unroll
          for (int i = 0; i < 4; ++i)
            if (kloc > w * 16 + quad * 4 + i) sc[nb][i] = NEG_BIG;
        }
      }

      // ---- online softmax (rows = quad*4+i; max-reduce over the quad's 16 lanes) ----
      float alpha[4];
#pragma unroll
      for (int i = 0; i < 4; ++i) {
        float m = fmaxf(fmaxf(sc[0][i], sc[1][i]), fmaxf(sc[2][i], sc[3][i]));
        m = fmaxf(m, __shfl_xor(m, 1));
        m = fmaxf(m, __shfl_xor(m, 2));
        m = fmaxf(m, __shfl_xor(m, 4));
        m = fmaxf(m, __shfl_xor(m, 8));
        float Mn = fmaxf(m_i[i], m);
        alpha[i] = __expf(m_i[i] - Mn);
        m_i[i] = Mn;
      }
      float rs[4] = {0.f, 0.f, 0.f, 0.f};
#pragma unroll
      for (int nb = 0; nb < 4; ++nb)
#pragma unroll
        for (int i = 0; i < 4; ++i) {
          float pv = __expf(sc[nb][i] - m_i[i]);
          rs[i] += pv;
          sP[w][quad * 4 + i][nb * 16 + l15] = (short)__bfloat16_as_ushort(__float2bfloat16(pv));
        }
#pragma unroll
      for (int i = 0; i < 4; ++i) l_p[i] = l_p[i] * alpha[i] + rs[i];
#pragma unroll
      for (int d = 0; d < 4; ++d)
#pragma unroll
        for (int i = 0; i < 4; ++i) oacc[d][i] *= alpha[i];

      // ---- O += P V (P via per-wave LDS round-trip; V^T with swizzled cols) ----
#pragma unroll
      for (int kk = 0; kk < 2; ++kk) {
        bf16x8 afr = __builtin_bit_cast(bf16x8,
            *(const shortx8*)&sP[w][l15][kk * 32 + quad * 8]);
#pragma unroll
        for (int db = 0; db < 4; ++db) {
          int row = db * 16 + l15;
          int col = (kk * 32 + quad * 8 + (row & 56)) & 63;
          bf16x8 bfr = __builtin_bit_cast(bf16x8, *(const shortx8*)&sVt[row][col]);
          oacc[db] = __builtin_amdgcn_mfma_f32_16x16x32_bf16(afr, bfr, oacc[db], 0, 0, 0);
        }
      }
      __syncthreads();  // before next tile overwrites sK/sVt
    }

    // ---- epilogue: reduce lane-partial l across the quad, store O rows ----
#pragma unroll
    for (int i = 0; i < 4; ++i) {
      float l = l_p[i];
      l += __shfl_xor(l, 1);
      l += __shfl_xor(l, 2);
      l += __shfl_xor(l, 4);
      l += __shfl_xor(l, 8);
      float inv = 1.f / l;
      bf16* op = O + (size_t)(b * S + q0 + w * 16 + quad * 4 + i) * D + h * 64 + l15;
#pragma unroll
      for (int d = 0; d < 4; ++d)
        op[d * 16] = __float2bfloat16(oacc[d][i] * inv);
    }
  }
}

// ---------------- launch ----------------
// ws layout (bf16 elements from ws16 = d_ws + 16; flag int at d_ws):
//   xb 8.4M | cosb/sinb 131k | bt_qkv 6.3M | wot 4.2M | qkv 12.6M  (~63.4 MB)
extern "C" void kernel_launch(void* const* d_in, const int* in_sizes, int n_in,
                              void* d_out, int out_size, void* d_ws, size_t ws_size,
                              hipStream_t stream) {
  const void* x    = d_in[0];
  const void* cosp = d_in[1];
  const void* sinp = d_in[2];
  const void* wq   = d_in[3];
  const void* wk   = d_in[4];
  const void* wv   = d_in[5];
  const void* wo   = d_in[6];

  int* flag = (int*)d_ws;
  bf16* ws16 = (bf16*)((char*)d_ws + 16);
  bf16* xb     = ws16;
  bf16* cosb   = xb + (size_t)8388608;
  bf16* sinb   = cosb + 131072;
  bf16* bt_qkv = sinb + 131072;
  bf16* wot    = bt_qkv + (size_t)3072 * 2048;
  bf16* qkv    = wot + (size_t)2048 * 2048;
  bf16* o      = xb;  // x dead after QKV GEMM; attn output reuses it

  sniff_k<<<1, 1, 0, stream>>>(cosp, flag);

  conv_k<<<(8388608 + 255) / 256, 256, 0, stream>>>(x, xb, 8388608, flag);
  conv_k<<<(131072 + 255) / 256, 256, 0, stream>>>(cosp, cosb, 131072, flag);
  conv_k<<<(131072 + 255) / 256, 256, 0, stream>>>(sinp, sinb, 131072, flag);

  dim3 tb(32, 8);
  transpose_conv_k<<<dim3(64, 64), tb, 0, stream>>>(wq, bt_qkv, 2048, flag);
  transpose_conv_k<<<dim3(16, 64), tb, 0, stream>>>(wk, bt_qkv + (size_t)2048 * 2048, 512, flag);
  transpose_conv_k<<<dim3(16, 64), tb, 0, stream>>>(wv, bt_qkv + (size_t)2560 * 2048, 512, flag);
  transpose_conv_k<<<dim3(64, 64), tb, 0, stream>>>(wo, wot, 2048, flag);

  // QKV projection: (4096,2048) @ (2048,3072), bf16 out
  gemm_bt<<<dim3(3072 / BN, 4096 / BM), 256, 0, stream>>>(xb, bt_qkv, qkv,
                                                          4096, 3072, 2048, flag, 0);

  rope_k<<<20480, 256, 0, stream>>>(qkv, cosb, sinb);

  // attention: grid (q-tile pairs, heads, batch) — balanced causal work
  attn_k<<<dim3(16, 32, 2), 256, 0, stream>>>(qkv, o);

  // output projection: (4096,2048) @ (2048,2048); output dtype follows input dtype
  gemm_bt<<<dim3(2048 / BN, 4096 / BM), 256, 0, stream>>>(o, wot, d_out,
                                                          4096, 2048, 2048, flag, 1);
}

// Round 6
// 453.106 us; speedup vs baseline: 4.5035x; 1.0093x over previous
//
#include <hip/hip_runtime.h>
#include <hip/hip_bf16.h>

using bf16 = __hip_bfloat16;

typedef float floatx4 __attribute__((ext_vector_type(4)));
typedef short shortx8 __attribute__((ext_vector_type(8)));
typedef __bf16 bf16x8 __attribute__((ext_vector_type(8)));

#define NEG_BIG -3.0e38f

// async global->LDS DMA, 16 B per lane; LDS dest = wave-uniform base + lane*16
#define GLOAD_LDS16(g, l)                                                     \
  __builtin_amdgcn_global_load_lds(                                           \
      (const __attribute__((address_space(1))) unsigned int*)(g),             \
      (__attribute__((address_space(3))) unsigned int*)(l), 16, 0, 0)

__device__ __forceinline__ float bf2f(short s) {
  union { unsigned int u; float f; } x;
  x.u = ((unsigned int)(unsigned short)s) << 16;
  return x.f;
}

// ---------------- dtype sniff: cos[0]==1.0 exactly.
// fp32 -> word0 = 0x3F800000 ; bf16 -> word0 = 0x3F803F80 (two packed 1.0's)
__global__ void sniff_k(const void* __restrict__ cosp, int* __restrict__ flag) {
  unsigned w = *(const unsigned*)cosp;
  *flag = (w == 0x3F800000u) ? 1 : 0;  // 1 = inputs are fp32
}

// ---------------- generic input -> bf16 convert (flag-aware) ----------------
__global__ void conv_k(const void* __restrict__ src, bf16* __restrict__ dst, int n,
                       const int* __restrict__ flag) {
  int fp32 = *flag;
  int i = blockIdx.x * blockDim.x + threadIdx.x;
  if (i >= n) return;
  if (fp32) dst[i] = __float2bfloat16(((const float*)src)[i]);
  else      dst[i] = ((const bf16*)src)[i];
}

// ---------------- fused convert + transpose: src (2048, C) -> dst (C, 2048) bf16 ------
__global__ void transpose_conv_k(const void* __restrict__ src, bf16* __restrict__ dst,
                                 int C, const int* __restrict__ flag) {
  __shared__ bf16 tile[32][33];
  int fp32 = *flag;
  int tx = threadIdx.x, ty = threadIdx.y;
  int c0 = blockIdx.x * 32, r0 = blockIdx.y * 32;
#pragma unroll
  for (int i = 0; i < 32; i += 8) {
    size_t idx = (size_t)(r0 + ty + i) * C + c0 + tx;
    tile[ty + i][tx] = fp32 ? __float2bfloat16(((const float*)src)[idx])
                            : ((const bf16*)src)[idx];
  }
  __syncthreads();
#pragma unroll
  for (int i = 0; i < 32; i += 8)
    dst[(size_t)(c0 + ty + i) * 2048 + r0 + tx] = tile[tx][ty + i];
}

// ---------------- GEMM: C(M,N) = A(M,K) @ Bt(N,K)^T, bf16 in, fp32 acc ----------------
// m97-style staging: global_load_lds width=16 into UNPADDED [128][32] LDS tiles.
// Wave w DMAs rows [w*16, w*16+16) and [64+w*16, ...): lane i -> row w*16+i/4,
// col (i&3)*8; LDS linear offset i*16B == row-major [row][32] exactly.
#define BM 128
#define BN 128
#define BK 32

__global__ __launch_bounds__(256) void gemm_bt(const bf16* __restrict__ A,
                                               const bf16* __restrict__ Bt,
                                               void* __restrict__ Cp,
                                               int M, int N, int K,
                                               const int* __restrict__ flag,
                                               int f32out_en) {
  __shared__ __align__(16) short sA[BM][BK];
  __shared__ __align__(16) short sB[BN][BK];
  const int f32out = f32out_en ? *flag : 0;
  const int tid = threadIdx.x;
  const int wave = tid >> 6, lane = tid & 63;
  const int wr = wave >> 1, wc = wave & 1;
  const int lrow = lane & 15, quad = lane >> 4;
  const int m0 = blockIdx.y * BM, n0 = blockIdx.x * BN;

  floatx4 acc[4][4];
#pragma unroll
  for (int r = 0; r < 4; ++r)
#pragma unroll
    for (int c = 0; c < 4; ++c)
      acc[r][c] = (floatx4){0.f, 0.f, 0.f, 0.f};

  const int l4r = lane >> 2;        // 0..15: row within wave chunk
  const int l4c = (lane & 3) * 8;   // col segment (8 bf16 = 16 B)
  const bf16* gA0 = A  + (size_t)(m0 + wave * 16 + l4r) * K + l4c;
  const bf16* gA1 = gA0 + (size_t)64 * K;
  const bf16* gB0 = Bt + (size_t)(n0 + wave * 16 + l4r) * K + l4c;
  const bf16* gB1 = gB0 + (size_t)64 * K;
  short* ldsA0 = &sA[wave * 16][0];
  short* ldsA1 = &sA[64 + wave * 16][0];
  short* ldsB0 = &sB[wave * 16][0];
  short* ldsB1 = &sB[64 + wave * 16][0];

  for (int kk = 0; kk < K; kk += BK) {
    GLOAD_LDS16(gA0 + kk, ldsA0);
    GLOAD_LDS16(gA1 + kk, ldsA1);
    GLOAD_LDS16(gB0 + kk, ldsB0);
    GLOAD_LDS16(gB1 + kk, ldsB1);
    __syncthreads();  // drains vmcnt (DMA complete) + barrier

    bf16x8 af[4], bfr[4];
#pragma unroll
    for (int r = 0; r < 4; ++r)
      af[r] = __builtin_bit_cast(bf16x8, *(const shortx8*)&sA[wr * 64 + r * 16 + lrow][quad * 8]);
#pragma unroll
    for (int c = 0; c < 4; ++c)
      bfr[c] = __builtin_bit_cast(bf16x8, *(const shortx8*)&sB[wc * 64 + c * 16 + lrow][quad * 8]);
#pragma unroll
    for (int r = 0; r < 4; ++r)
#pragma unroll
      for (int c = 0; c < 4; ++c)
        acc[r][c] = __builtin_amdgcn_mfma_f32_16x16x32_bf16(af[r], bfr[c], acc[r][c], 0, 0, 0);
    __syncthreads();
  }

#pragma unroll
  for (int r = 0; r < 4; ++r) {
#pragma unroll
    for (int c = 0; c < 4; ++c) {
      int mrow = m0 + wr * 64 + r * 16 + quad * 4;
      int ncol = n0 + wc * 64 + c * 16 + lrow;
      if (f32out) {
#pragma unroll
        for (int i = 0; i < 4; ++i)
          ((float*)Cp)[(size_t)(mrow + i) * N + ncol] = acc[r][c][i];
      } else {
#pragma unroll
        for (int i = 0; i < 4; ++i)
          ((bf16*)Cp)[(size_t)(mrow + i) * N + ncol] = __float2bfloat16(acc[r][c][i]);
      }
    }
  }
}

// ---------------- RoPE in-place on q (heads 0..31) and k (kv heads 0..7) ----------------
__global__ void rope_k(bf16* __restrict__ qkv, const bf16* __restrict__ cosb,
                       const bf16* __restrict__ sinb) {
  int idx = blockIdx.x * blockDim.x + threadIdx.x;
  int i = idx & 31;
  int head = (idx >> 5) % 40;
  int m = idx / (32 * 40);
  if (m >= 4096) return;
  int p = m & 2047;
  size_t base = (size_t)m * 3072 + (head < 32 ? head * 64 : 2048 + (head - 32) * 64);
  float c0 = __bfloat162float(cosb[p * 64 + i]);
  float s0 = __bfloat162float(sinb[p * 64 + i]);
  float c1 = __bfloat162float(cosb[p * 64 + 32 + i]);
  float s1 = __bfloat162float(sinb[p * 64 + 32 + i]);
  float a  = __bfloat162float(qkv[base + i]);
  float bb = __bfloat162float(qkv[base + 32 + i]);
  qkv[base + i]      = __float2bfloat16(a * c0 - bb * s0);
  qkv[base + 32 + i] = __float2bfloat16(bb * c1 + a * s1);
}

// ---------------- flash attention (causal, GQA 4:1) — MFMA, balanced + prefetch ------
// (unchanged from R5 — 142 µs, correctness-verified)
__global__ __launch_bounds__(256) void attn_k(const bf16* __restrict__ qkv,
                                              bf16* __restrict__ O) {
  const int S = 2048, LDQ = 3072, D = 2048;
  const int p = blockIdx.x, h = blockIdx.y, b = blockIdx.z;
  const int kvh = h >> 2;
  const int tid = threadIdx.x;
  const int w = tid >> 6, lane = tid & 63;
  const int quad = lane >> 4, l15 = lane & 15;

  __shared__ __align__(16) short sK [64][72];
  __shared__ __align__(16) short sVt[64][72];
  __shared__ __align__(16) short sP [4][16][72];

  const int srow = tid >> 2, sseg = (tid & 3) * 16;
  const bf16* kvbase = qkv + (size_t)(b * S) * LDQ + 2048 + kvh * 64 + sseg;

  for (int phase = 0; phase < 2; ++phase) {
    const int qt = phase ? (31 - p) : p;
    const int q0 = qt * 64;

    bf16x8 qa[2];
    {
      const bf16* qp = qkv + (size_t)(b * S + q0 + w * 16 + l15) * LDQ + h * 64 + quad * 8;
      qa[0] = __builtin_bit_cast(bf16x8, *(const shortx8*)qp);
      qa[1] = __builtin_bit_cast(bf16x8, *(const shortx8*)(qp + 32));
    }

    floatx4 oacc[4];
#pragma unroll
    for (int d = 0; d < 4; ++d) oacc[d] = (floatx4){0.f, 0.f, 0.f, 0.f};
    float m_i[4], l_p[4];
#pragma unroll
    for (int i = 0; i < 4; ++i) { m_i[i] = NEG_BIG; l_p[i] = 0.f; }

    const int jtEnd = qt + 1;
    const bf16* kp = kvbase + (size_t)srow * LDQ;
    int4 kr0 = *(const int4*)kp;
    int4 kr1 = *(const int4*)(kp + 8);
    int4 vr0 = *(const int4*)(kp + 512);
    int4 vr1 = *(const int4*)(kp + 520);

    for (int jt = 0; jt < jtEnd; ++jt) {
      *(int4*)&sK[srow][sseg]     = kr0;
      *(int4*)&sK[srow][sseg + 8] = kr1;
      {
        const short* v0s = (const short*)&vr0;
        const short* v1s = (const short*)&vr1;
#pragma unroll
        for (int e = 0; e < 8; ++e) {
          int d = sseg + e;
          sVt[d][(srow + (d & 56)) & 63] = v0s[e];
        }
#pragma unroll
        for (int e = 0; e < 8; ++e) {
          int d = sseg + 8 + e;
          sVt[d][(srow + (d & 56)) & 63] = v1s[e];
        }
      }
      if (jt + 1 < jtEnd) {
        const bf16* kp2 = kvbase + (size_t)((jt + 1) * 64 + srow) * LDQ;
        kr0 = *(const int4*)kp2;
        kr1 = *(const int4*)(kp2 + 8);
        vr0 = *(const int4*)(kp2 + 512);
        vr1 = *(const int4*)(kp2 + 520);
      }
      __syncthreads();

      floatx4 sfr[4];
#pragma unroll
      for (int nb = 0; nb < 4; ++nb) sfr[nb] = (floatx4){0.f, 0.f, 0.f, 0.f};
#pragma unroll
      for (int kk = 0; kk < 2; ++kk) {
#pragma unroll
        for (int nb = 0; nb < 4; ++nb) {
          bf16x8 bfr = __builtin_bit_cast(bf16x8,
              *(const shortx8*)&sK[nb * 16 + l15][kk * 32 + quad * 8]);
          sfr[nb] = __builtin_amdgcn_mfma_f32_16x16x32_bf16(qa[kk], bfr, sfr[nb], 0, 0, 0);
        }
      }

      float sc[4][4];
#pragma unroll
      for (int nb = 0; nb < 4; ++nb)
#pragma unroll
        for (int i = 0; i < 4; ++i) sc[nb][i] = sfr[nb][i] * 0.125f;
      if (jt == qt) {
#pragma unroll
        for (int nb = 0; nb < 4; ++nb) {
          int kloc = nb * 16 + l15;
#pragma unroll
          for (int i = 0; i < 4; ++i)
            if (kloc > w * 16 + quad * 4 + i) sc[nb][i] = NEG_BIG;
        }
      }

      float alpha[4];
#pragma unroll
      for (int i = 0; i < 4; ++i) {
        float m = fmaxf(fmaxf(sc[0][i], sc[1][i]), fmaxf(sc[2][i], sc[3][i]));
        m = fmaxf(m, __shfl_xor(m, 1));
        m = fmaxf(m, __shfl_xor(m, 2));
        m = fmaxf(m, __shfl_xor(m, 4));
        m = fmaxf(m, __shfl_xor(m, 8));
        float Mn = fmaxf(m_i[i], m);
        alpha[i] = __expf(m_i[i] - Mn);
        m_i[i] = Mn;
      }
      float rs[4] = {0.f, 0.f, 0.f, 0.f};
#pragma unroll
      for (int nb = 0; nb < 4; ++nb)
#pragma unroll
        for (int i = 0; i < 4; ++i) {
          float pv = __expf(sc[nb][i] - m_i[i]);
          rs[i] += pv;
          sP[w][quad * 4 + i][nb * 16 + l15] = (short)__bfloat16_as_ushort(__float2bfloat16(pv));
        }
#pragma unroll
      for (int i = 0; i < 4; ++i) l_p[i] = l_p[i] * alpha[i] + rs[i];
#pragma unroll
      for (int d = 0; d < 4; ++d)
#pragma unroll
        for (int i = 0; i < 4; ++i) oacc[d][i] *= alpha[i];

#pragma unroll
      for (int kk = 0; kk < 2; ++kk) {
        bf16x8 afr = __builtin_bit_cast(bf16x8,
            *(const shortx8*)&sP[w][l15][kk * 32 + quad * 8]);
#pragma unroll
        for (int db = 0; db < 4; ++db) {
          int row = db * 16 + l15;
          int col = (kk * 32 + quad * 8 + (row & 56)) & 63;
          bf16x8 bfr = __builtin_bit_cast(bf16x8, *(const shortx8*)&sVt[row][col]);
          oacc[db] = __builtin_amdgcn_mfma_f32_16x16x32_bf16(afr, bfr, oacc[db], 0, 0, 0);
        }
      }
      __syncthreads();
    }

#pragma unroll
    for (int i = 0; i < 4; ++i) {
      float l = l_p[i];
      l += __shfl_xor(l, 1);
      l += __shfl_xor(l, 2);
      l += __shfl_xor(l, 4);
      l += __shfl_xor(l, 8);
      float inv = 1.f / l;
      bf16* op = O + (size_t)(b * S + q0 + w * 16 + quad * 4 + i) * D + h * 64 + l15;
#pragma unroll
      for (int d = 0; d < 4; ++d)
        op[d * 16] = __float2bfloat16(oacc[d][i] * inv);
    }
  }
}

// ---------------- launch ----------------
// ws layout (bf16 elements from ws16 = d_ws + 16; flag int at d_ws):
//   xb 8.4M | cosb/sinb 131k | bt_qkv 6.3M | wot 4.2M | qkv 12.6M  (~63.4 MB)
extern "C" void kernel_launch(void* const* d_in, const int* in_sizes, int n_in,
                              void* d_out, int out_size, void* d_ws, size_t ws_size,
                              hipStream_t stream) {
  const void* x    = d_in[0];
  const void* cosp = d_in[1];
  const void* sinp = d_in[2];
  const void* wq   = d_in[3];
  const void* wk   = d_in[4];
  const void* wv   = d_in[5];
  const void* wo   = d_in[6];

  int* flag = (int*)d_ws;
  bf16* ws16 = (bf16*)((char*)d_ws + 16);
  bf16* xb     = ws16;
  bf16* cosb   = xb + (size_t)8388608;
  bf16* sinb   = cosb + 131072;
  bf16* bt_qkv = sinb + 131072;
  bf16* wot    = bt_qkv + (size_t)3072 * 2048;
  bf16* qkv    = wot + (size_t)2048 * 2048;
  bf16* o      = xb;  // x dead after QKV GEMM; attn output reuses it

  sniff_k<<<1, 1, 0, stream>>>(cosp, flag);

  conv_k<<<(8388608 + 255) / 256, 256, 0, stream>>>(x, xb, 8388608, flag);
  conv_k<<<(131072 + 255) / 256, 256, 0, stream>>>(cosp, cosb, 131072, flag);
  conv_k<<<(131072 + 255) / 256, 256, 0, stream>>>(sinp, sinb, 131072, flag);

  dim3 tb(32, 8);
  transpose_conv_k<<<dim3(64, 64), tb, 0, stream>>>(wq, bt_qkv, 2048, flag);
  transpose_conv_k<<<dim3(16, 64), tb, 0, stream>>>(wk, bt_qkv + (size_t)2048 * 2048, 512, flag);
  transpose_conv_k<<<dim3(16, 64), tb, 0, stream>>>(wv, bt_qkv + (size_t)2560 * 2048, 512, flag);
  transpose_conv_k<<<dim3(64, 64), tb, 0, stream>>>(wo, wot, 2048, flag);

  // QKV projection: (4096,2048) @ (2048,3072), bf16 out
  gemm_bt<<<dim3(3072 / BN, 4096 / BM), 256, 0, stream>>>(xb, bt_qkv, qkv,
                                                          4096, 3072, 2048, flag, 0);

  rope_k<<<20480, 256, 0, stream>>>(qkv, cosb, sinb);

  // attention: grid (q-tile pairs, heads, batch) — balanced causal work
  attn_k<<<dim3(16, 32, 2), 256, 0, stream>>>(qkv, o);

  // output projection: (4096,2048) @ (2048,2048); output dtype follows input dtype
  gemm_bt<<<dim3(2048 / BN, 4096 / BM), 256, 0, stream>>>(o, wot, d_out,
                                                          4096, 2048, 2048, flag, 1);
}

// Round 7
// 436.451 us; speedup vs baseline: 4.6754x; 1.0382x over previous
//
#include <hip/hip_runtime.h>
#include <hip/hip_bf16.h>

using bf16 = __hip_bfloat16;

typedef float floatx4 __attribute__((ext_vector_type(4)));
typedef short shortx8 __attribute__((ext_vector_type(8)));
typedef __bf16 bf16x8 __attribute__((ext_vector_type(8)));

#define NEG_BIG -3.0e38f

// async global->LDS DMA, 16 B per lane; LDS dest = wave-uniform base + lane*16
#define GLOAD_LDS16(g, l)                                                     \
  __builtin_amdgcn_global_load_lds(                                           \
      (const __attribute__((address_space(1))) unsigned int*)(g),             \
      (__attribute__((address_space(3))) unsigned int*)(l), 16, 0, 0)

__device__ __forceinline__ float bf2f(short s) {
  union { unsigned int u; float f; } x;
  x.u = ((unsigned int)(unsigned short)s) << 16;
  return x.f;
}

// ---------------- dtype sniff: cos[0]==1.0 exactly.
// fp32 -> word0 = 0x3F800000 ; bf16 -> word0 = 0x3F803F80 (two packed 1.0's)
__global__ void sniff_k(const void* __restrict__ cosp, int* __restrict__ flag) {
  unsigned w = *(const unsigned*)cosp;
  *flag = (w == 0x3F800000u) ? 1 : 0;  // 1 = inputs are fp32
}

// ---------------- generic input -> bf16 convert (flag-aware) ----------------
__global__ void conv_k(const void* __restrict__ src, bf16* __restrict__ dst, int n,
                       const int* __restrict__ flag) {
  int fp32 = *flag;
  int i = blockIdx.x * blockDim.x + threadIdx.x;
  if (i >= n) return;
  if (fp32) dst[i] = __float2bfloat16(((const float*)src)[i]);
  else      dst[i] = ((const bf16*)src)[i];
}

// ---------------- fused convert + transpose: src (2048, C) -> dst (C, 2048) bf16 ------
__global__ void transpose_conv_k(const void* __restrict__ src, bf16* __restrict__ dst,
                                 int C, const int* __restrict__ flag) {
  __shared__ bf16 tile[32][33];
  int fp32 = *flag;
  int tx = threadIdx.x, ty = threadIdx.y;
  int c0 = blockIdx.x * 32, r0 = blockIdx.y * 32;
#pragma unroll
  for (int i = 0; i < 32; i += 8) {
    size_t idx = (size_t)(r0 + ty + i) * C + c0 + tx;
    tile[ty + i][tx] = fp32 ? __float2bfloat16(((const float*)src)[idx])
                            : ((const bf16*)src)[idx];
  }
  __syncthreads();
#pragma unroll
  for (int i = 0; i < 32; i += 8)
    dst[(size_t)(c0 + ty + i) * 2048 + r0 + tx] = tile[tx][ty + i];
}

// ---------------- GEMM: C(M,N) = A(M,K) @ Bt(N,K)^T, bf16 in, fp32 acc ----------------
// m97-style staging: global_load_lds width=16 into UNPADDED [128][32] LDS tiles.
#define BM 128
#define BN 128
#define BK 32

__global__ __launch_bounds__(256) void gemm_bt(const bf16* __restrict__ A,
                                               const bf16* __restrict__ Bt,
                                               void* __restrict__ Cp,
                                               int M, int N, int K,
                                               const int* __restrict__ flag,
                                               int f32out_en) {
  __shared__ __align__(16) short sA[BM][BK];
  __shared__ __align__(16) short sB[BN][BK];
  const int f32out = f32out_en ? *flag : 0;
  const int tid = threadIdx.x;
  const int wave = tid >> 6, lane = tid & 63;
  const int wr = wave >> 1, wc = wave & 1;
  const int lrow = lane & 15, quad = lane >> 4;
  const int m0 = blockIdx.y * BM, n0 = blockIdx.x * BN;

  floatx4 acc[4][4];
#pragma unroll
  for (int r = 0; r < 4; ++r)
#pragma unroll
    for (int c = 0; c < 4; ++c)
      acc[r][c] = (floatx4){0.f, 0.f, 0.f, 0.f};

  const int l4r = lane >> 2;        // 0..15: row within wave chunk
  const int l4c = (lane & 3) * 8;   // col segment (8 bf16 = 16 B)
  const bf16* gA0 = A  + (size_t)(m0 + wave * 16 + l4r) * K + l4c;
  const bf16* gA1 = gA0 + (size_t)64 * K;
  const bf16* gB0 = Bt + (size_t)(n0 + wave * 16 + l4r) * K + l4c;
  const bf16* gB1 = gB0 + (size_t)64 * K;
  short* ldsA0 = &sA[wave * 16][0];
  short* ldsA1 = &sA[64 + wave * 16][0];
  short* ldsB0 = &sB[wave * 16][0];
  short* ldsB1 = &sB[64 + wave * 16][0];

  for (int kk = 0; kk < K; kk += BK) {
    GLOAD_LDS16(gA0 + kk, ldsA0);
    GLOAD_LDS16(gA1 + kk, ldsA1);
    GLOAD_LDS16(gB0 + kk, ldsB0);
    GLOAD_LDS16(gB1 + kk, ldsB1);
    __syncthreads();  // drains vmcnt (DMA complete) + barrier

    bf16x8 af[4], bfr[4];
#pragma unroll
    for (int r = 0; r < 4; ++r)
      af[r] = __builtin_bit_cast(bf16x8, *(const shortx8*)&sA[wr * 64 + r * 16 + lrow][quad * 8]);
#pragma unroll
    for (int c = 0; c < 4; ++c)
      bfr[c] = __builtin_bit_cast(bf16x8, *(const shortx8*)&sB[wc * 64 + c * 16 + lrow][quad * 8]);
#pragma unroll
    for (int r = 0; r < 4; ++r)
#pragma unroll
      for (int c = 0; c < 4; ++c)
        acc[r][c] = __builtin_amdgcn_mfma_f32_16x16x32_bf16(af[r], bfr[c], acc[r][c], 0, 0, 0);
    __syncthreads();
  }

#pragma unroll
  for (int r = 0; r < 4; ++r) {
#pragma unroll
    for (int c = 0; c < 4; ++c) {
      int mrow = m0 + wr * 64 + r * 16 + quad * 4;
      int ncol = n0 + wc * 64 + c * 16 + lrow;
      if (f32out) {
#pragma unroll
        for (int i = 0; i < 4; ++i)
          ((float*)Cp)[(size_t)(mrow + i) * N + ncol] = acc[r][c][i];
      } else {
#pragma unroll
        for (int i = 0; i < 4; ++i)
          ((bf16*)Cp)[(size_t)(mrow + i) * N + ncol] = __float2bfloat16(acc[r][c][i]);
      }
    }
  }
}

// ---------------- RoPE in-place on q (heads 0..31) and k (kv heads 0..7) ----------------
__global__ void rope_k(bf16* __restrict__ qkv, const bf16* __restrict__ cosb,
                       const bf16* __restrict__ sinb) {
  int idx = blockIdx.x * blockDim.x + threadIdx.x;
  int i = idx & 31;
  int head = (idx >> 5) % 40;
  int m = idx / (32 * 40);
  if (m >= 4096) return;
  int p = m & 2047;
  size_t base = (size_t)m * 3072 + (head < 32 ? head * 64 : 2048 + (head - 32) * 64);
  float c0 = __bfloat162float(cosb[p * 64 + i]);
  float s0 = __bfloat162float(sinb[p * 64 + i]);
  float c1 = __bfloat162float(cosb[p * 64 + 32 + i]);
  float s1 = __bfloat162float(sinb[p * 64 + 32 + i]);
  float a  = __bfloat162float(qkv[base + i]);
  float bb = __bfloat162float(qkv[base + 32 + i]);
  qkv[base + i]      = __float2bfloat16(a * c0 - bb * s0);
  qkv[base + 32 + i] = __float2bfloat16(bb * c1 + a * s1);
}

// ---------------- flash attention (causal, GQA 4:1) — MFMA, 128-row Q-tile ----------
// Q-tile 128 rows/block (32/wave, 2 sub-tiles of 16); K/V tiles 64.
// Shared K and V^T B-frag LDS reads amortized over both sub-tiles (DS-instr bound:
// 528 -> 744 DS cyc/wave-iter for 2x work = -30% per work, per m134 cycle model).
// Pairing qt=p with 15-p gives constant 34 kv-iters/block; grid 8x32x2 = 512.
__global__ __launch_bounds__(256) void attn_k(const bf16* __restrict__ qkv,
                                              bf16* __restrict__ O) {
  const int S = 2048, LDQ = 3072, D = 2048;
  const int p = blockIdx.x, h = blockIdx.y, b = blockIdx.z;
  const int kvh = h >> 2;
  const int tid = threadIdx.x;
  const int w = tid >> 6, lane = tid & 63;
  const int quad = lane >> 4, l15 = lane & 15;

  __shared__ __align__(16) short sK [64][72];    // [kv pos][hd]
  __shared__ __align__(16) short sVt[64][72];    // [hd][swizzled kv pos]
  __shared__ __align__(16) short sP [4][32][72]; // per-wave P round-trip (32 rows)

  const int srow = tid >> 2, sseg = (tid & 3) * 16;
  const bf16* kvbase = qkv + (size_t)(b * S) * LDQ + 2048 + kvh * 64 + sseg;

  for (int phase = 0; phase < 2; ++phase) {
    const int qt = phase ? (15 - p) : p;
    const int q0 = qt * 128;

    // Q fragments: 2 sub-tiles x 2 k-halves
    bf16x8 qa[2][2];
#pragma unroll
    for (int mt = 0; mt < 2; ++mt) {
      const bf16* qp = qkv + (size_t)(b * S + q0 + w * 32 + mt * 16 + l15) * LDQ + h * 64 + quad * 8;
      qa[mt][0] = __builtin_bit_cast(bf16x8, *(const shortx8*)qp);
      qa[mt][1] = __builtin_bit_cast(bf16x8, *(const shortx8*)(qp + 32));
    }

    floatx4 oacc[2][4];
    float m_i[2][4], l_p[2][4];
#pragma unroll
    for (int mt = 0; mt < 2; ++mt) {
#pragma unroll
      for (int d = 0; d < 4; ++d) oacc[mt][d] = (floatx4){0.f, 0.f, 0.f, 0.f};
#pragma unroll
      for (int i = 0; i < 4; ++i) { m_i[mt][i] = NEG_BIG; l_p[mt][i] = 0.f; }
    }

    const int jtEnd = 2 * qt + 2;
    // prefetch tile 0
    const bf16* kp = kvbase + (size_t)srow * LDQ;
    int4 kr0 = *(const int4*)kp;
    int4 kr1 = *(const int4*)(kp + 8);
    int4 vr0 = *(const int4*)(kp + 512);
    int4 vr1 = *(const int4*)(kp + 520);

    for (int jt = 0; jt < jtEnd; ++jt) {
      // ---- stage prefetched K (row layout) and V (transposed, bank-swizzled) ----
      *(int4*)&sK[srow][sseg]     = kr0;
      *(int4*)&sK[srow][sseg + 8] = kr1;
      {
        const short* v0s = (const short*)&vr0;
        const short* v1s = (const short*)&vr1;
#pragma unroll
        for (int e = 0; e < 8; ++e) {
          int d = sseg + e;
          sVt[d][(srow + (d & 56)) & 63] = v0s[e];
        }
#pragma unroll
        for (int e = 0; e < 8; ++e) {
          int d = sseg + 8 + e;
          sVt[d][(srow + (d & 56)) & 63] = v1s[e];
        }
      }
      if (jt + 1 < jtEnd) {
        const bf16* kp2 = kvbase + (size_t)((jt + 1) * 64 + srow) * LDQ;
        kr0 = *(const int4*)kp2;
        kr1 = *(const int4*)(kp2 + 8);
        vr0 = *(const int4*)(kp2 + 512);
        vr1 = *(const int4*)(kp2 + 520);
      }
      __syncthreads();

      // ---- S = Q K^T: 32x64 per wave; K B-frags loaded once, shared by both mt ----
      floatx4 sfr[2][4];
#pragma unroll
      for (int mt = 0; mt < 2; ++mt)
#pragma unroll
        for (int nb = 0; nb < 4; ++nb) sfr[mt][nb] = (floatx4){0.f, 0.f, 0.f, 0.f};
#pragma unroll
      for (int kk = 0; kk < 2; ++kk) {
#pragma unroll
        for (int nb = 0; nb < 4; ++nb) {
          bf16x8 bfr = __builtin_bit_cast(bf16x8,
              *(const shortx8*)&sK[nb * 16 + l15][kk * 32 + quad * 8]);
          sfr[0][nb] = __builtin_amdgcn_mfma_f32_16x16x32_bf16(qa[0][kk], bfr, sfr[0][nb], 0, 0, 0);
          sfr[1][nb] = __builtin_amdgcn_mfma_f32_16x16x32_bf16(qa[1][kk], bfr, sfr[1][nb], 0, 0, 0);
        }
      }

      // ---- per sub-tile: scale, mask, online softmax, P store, O rescale ----
#pragma unroll
      for (int mt = 0; mt < 2; ++mt) {
        float sc[4][4];
#pragma unroll
        for (int nb = 0; nb < 4; ++nb)
#pragma unroll
          for (int i = 0; i < 4; ++i) sc[nb][i] = sfr[mt][nb][i] * 0.125f;
        if (jt >= 2 * qt) {  // only the two diagonal-crossing tiles need masking
#pragma unroll
          for (int nb = 0; nb < 4; ++nb) {
            int jg = jt * 64 + nb * 16 + l15;
#pragma unroll
            for (int i = 0; i < 4; ++i) {
              int rg = q0 + w * 32 + mt * 16 + quad * 4 + i;
              if (jg > rg) sc[nb][i] = NEG_BIG;
            }
          }
        }

        float alpha[4];
#pragma unroll
        for (int i = 0; i < 4; ++i) {
          float m = fmaxf(fmaxf(sc[0][i], sc[1][i]), fmaxf(sc[2][i], sc[3][i]));
          m = fmaxf(m, __shfl_xor(m, 1));
          m = fmaxf(m, __shfl_xor(m, 2));
          m = fmaxf(m, __shfl_xor(m, 4));
          m = fmaxf(m, __shfl_xor(m, 8));
          float Mn = fmaxf(m_i[mt][i], m);
          alpha[i] = __expf(m_i[mt][i] - Mn);
          m_i[mt][i] = Mn;
        }
        float rs[4] = {0.f, 0.f, 0.f, 0.f};
#pragma unroll
        for (int nb = 0; nb < 4; ++nb)
#pragma unroll
          for (int i = 0; i < 4; ++i) {
            float pv = __expf(sc[nb][i] - m_i[mt][i]);
            rs[i] += pv;
            sP[w][mt * 16 + quad * 4 + i][nb * 16 + l15] =
                (short)__bfloat16_as_ushort(__float2bfloat16(pv));
          }
#pragma unroll
        for (int i = 0; i < 4; ++i) l_p[mt][i] = l_p[mt][i] * alpha[i] + rs[i];
#pragma unroll
        for (int d = 0; d < 4; ++d)
#pragma unroll
          for (int i = 0; i < 4; ++i) oacc[mt][d][i] *= alpha[i];
      }

      // ---- O += P V: V^T B-frags loaded once, shared by both mt ----
#pragma unroll
      for (int kk = 0; kk < 2; ++kk) {
        bf16x8 af0 = __builtin_bit_cast(bf16x8,
            *(const shortx8*)&sP[w][l15][kk * 32 + quad * 8]);
        bf16x8 af1 = __builtin_bit_cast(bf16x8,
            *(const shortx8*)&sP[w][16 + l15][kk * 32 + quad * 8]);
#pragma unroll
        for (int db = 0; db < 4; ++db) {
          int row = db * 16 + l15;
          int col = (kk * 32 + quad * 8 + (row & 56)) & 63;
          bf16x8 bfr = __builtin_bit_cast(bf16x8, *(const shortx8*)&sVt[row][col]);
          oacc[0][db] = __builtin_amdgcn_mfma_f32_16x16x32_bf16(af0, bfr, oacc[0][db], 0, 0, 0);
          oacc[1][db] = __builtin_amdgcn_mfma_f32_16x16x32_bf16(af1, bfr, oacc[1][db], 0, 0, 0);
        }
      }
      __syncthreads();  // before next tile overwrites sK/sVt
    }

    // ---- epilogue: reduce lane-partial l across the quad, store O rows ----
#pragma unroll
    for (int mt = 0; mt < 2; ++mt) {
#pragma unroll
      for (int i = 0; i < 4; ++i) {
        float l = l_p[mt][i];
        l += __shfl_xor(l, 1);
        l += __shfl_xor(l, 2);
        l += __shfl_xor(l, 4);
        l += __shfl_xor(l, 8);
        float inv = 1.f / l;
        bf16* op = O + (size_t)(b * S + q0 + w * 32 + mt * 16 + quad * 4 + i) * D + h * 64 + l15;
#pragma unroll
        for (int d = 0; d < 4; ++d)
          op[d * 16] = __float2bfloat16(oacc[mt][d][i] * inv);
      }
    }
  }
}

// ---------------- launch ----------------
// ws layout (bf16 elements from ws16 = d_ws + 16; flag int at d_ws):
//   xb 8.4M | cosb/sinb 131k | bt_qkv 6.3M | wot 4.2M | qkv 12.6M  (~63.4 MB)
extern "C" void kernel_launch(void* const* d_in, const int* in_sizes, int n_in,
                              void* d_out, int out_size, void* d_ws, size_t ws_size,
                              hipStream_t stream) {
  const void* x    = d_in[0];
  const void* cosp = d_in[1];
  const void* sinp = d_in[2];
  const void* wq   = d_in[3];
  const void* wk   = d_in[4];
  const void* wv   = d_in[5];
  const void* wo   = d_in[6];

  int* flag = (int*)d_ws;
  bf16* ws16 = (bf16*)((char*)d_ws + 16);
  bf16* xb     = ws16;
  bf16* cosb   = xb + (size_t)8388608;
  bf16* sinb   = cosb + 131072;
  bf16* bt_qkv = sinb + 131072;
  bf16* wot    = bt_qkv + (size_t)3072 * 2048;
  bf16* qkv    = wot + (size_t)2048 * 2048;
  bf16* o      = xb;  // x dead after QKV GEMM; attn output reuses it

  sniff_k<<<1, 1, 0, stream>>>(cosp, flag);

  conv_k<<<(8388608 + 255) / 256, 256, 0, stream>>>(x, xb, 8388608, flag);
  conv_k<<<(131072 + 255) / 256, 256, 0, stream>>>(cosp, cosb, 131072, flag);
  conv_k<<<(131072 + 255) / 256, 256, 0, stream>>>(sinp, sinb, 131072, flag);

  dim3 tb(32, 8);
  transpose_conv_k<<<dim3(64, 64), tb, 0, stream>>>(wq, bt_qkv, 2048, flag);
  transpose_conv_k<<<dim3(16, 64), tb, 0, stream>>>(wk, bt_qkv + (size_t)2048 * 2048, 512, flag);
  transpose_conv_k<<<dim3(16, 64), tb, 0, stream>>>(wv, bt_qkv + (size_t)2560 * 2048, 512, flag);
  transpose_conv_k<<<dim3(64, 64), tb, 0, stream>>>(wo, wot, 2048, flag);

  // QKV projection: (4096,2048) @ (2048,3072), bf16 out
  gemm_bt<<<dim3(3072 / BN, 4096 / BM), 256, 0, stream>>>(xb, bt_qkv, qkv,
                                                          4096, 3072, 2048, flag, 0);

  rope_k<<<20480, 256, 0, stream>>>(qkv, cosb, sinb);

  // attention: grid (q-tile pairs of 128 rows, heads, batch)
  attn_k<<<dim3(8, 32, 2), 256, 0, stream>>>(qkv, o);

  // output projection: (4096,2048) @ (2048,2048); output dtype follows input dtype
  gemm_bt<<<dim3(2048 / BN, 4096 / BM), 256, 0, stream>>>(o, wot, d_out,
                                                          4096, 2048, 2048, flag, 1);
}